// Round 9
// baseline (210.412 us; speedup 1.0000x reference)
//
#include <hip/hip_runtime.h>
#include <math.h>

typedef _Float16 f16;
typedef _Float16 f16x2 __attribute__((ext_vector_type(2)));
typedef _Float16 f16x4 __attribute__((ext_vector_type(4)));
typedef _Float16 f16x8 __attribute__((ext_vector_type(8)));
typedef float    f32x4 __attribute__((ext_vector_type(4)));
typedef float    f32x16 __attribute__((ext_vector_type(16)));

#define NSEQ 1024
#define CD   128
#define LT   136   // pre-kernel LDS f16 row stride (272 B = 17*16 B, keeps b128 alignment)

// ---- 32x32x16 fragment-linear workspace layouts (8 KB per 32-key tile) ----
// khs: [bh][kt 0..31][cs16 0..7][lane 0..63][j 0..7]
//   value = Ktr[key = kt*32 + (lane&31)][c = cs16*16 + 8*(lane>>5) + j]
//   = exact A-operand fragment of mfma_32x32x16 (row = lane&31, k = 8*(lane>>5)+j).
// vhs: [bh][kt 0..31][cb 0..3][kh 0..1][lane 0..63][j 0..7]
//   value = Vtr[c = cb*32 + (lane&31)][key = kt*32 + kh*16 + 8*(lane>>5) + j]
//   = exact A-operand fragment for PV (rows = c, k = key16 of half kh).
// A wave's fragment load = one coalesced 1KB dwordx4 burst at base + lane*16.

__global__ __launch_bounds__(256)
void ipa_pre(const float* __restrict__ kg, const float* __restrict__ vg,
             const float* __restrict__ Lm, f16* __restrict__ khs, f16* __restrict__ vhs)
{
    __shared__ float LL[64 * 16];
    __shared__ __align__(16) f16 Kt[64 * LT];
    __shared__ __align__(16) f16 Vt[64 * LT];
    const int bx = blockIdx.x, nt = blockIdx.y, tid = threadIdx.x;
    const int bh = ((bx & 7) << 3) | (bx >> 3);   // XCD x <-> bh 8x..8x+7 (matches attn)
    const int b  = bh >> 3;
    const float* Lb = Lm + ((size_t)b * NSEQ + nt * 64) * 16;
    for (int t = tid; t < 64 * 16; t += 256) LL[t] = Lb[t];
    __syncthreads();

    const size_t base = ((size_t)bh * NSEQ + nt * 64) * CD;
    #pragma unroll
    for (int it = 0; it < 8; ++it) {
        int g = it * 256 + tid;
        int row = g >> 5, cg = g & 31;
        size_t idx = base + row * CD + cg * 4;
        const float* Lr = &LL[row * 16];
        float4 xk = *(const float4*)(kg + idx);
        float4 xv = *(const float4*)(vg + idx);
        float4 yk = xk, yv = xv;
        if (cg >= 2) {
            float t0 = xk.x, t1 = -xk.y, t2 = -xk.z, t3 = -xk.w;   // K: M = L^T eta
            yk.x = Lr[0]*t0 + Lr[4]*t1 + Lr[8] *t2 + Lr[12]*t3;
            yk.y = Lr[1]*t0 + Lr[5]*t1 + Lr[9] *t2 + Lr[13]*t3;
            yk.z = Lr[2]*t0 + Lr[6]*t1 + Lr[10]*t2 + Lr[14]*t3;
            yk.w = Lr[3]*t0 + Lr[7]*t1 + Lr[11]*t2 + Lr[15]*t3;
            t0 = xv.x; t1 = -xv.y; t2 = -xv.z; t3 = -xv.w;         // V: M = eta L^T eta
            yv.x =  (Lr[0]*t0 + Lr[4]*t1 + Lr[8] *t2 + Lr[12]*t3);
            yv.y = -(Lr[1]*t0 + Lr[5]*t1 + Lr[9] *t2 + Lr[13]*t3);
            yv.z = -(Lr[2]*t0 + Lr[6]*t1 + Lr[10]*t2 + Lr[14]*t3);
            yv.w = -(Lr[3]*t0 + Lr[7]*t1 + Lr[11]*t2 + Lr[15]*t3);
        }
        f16x4 hk = {(f16)yk.x, (f16)yk.y, (f16)yk.z, (f16)yk.w};
        f16x4 hv = {(f16)yv.x, (f16)yv.y, (f16)yv.z, (f16)yv.w};
        *(f16x4*)&Kt[row * LT + cg * 4] = hk;
        *(f16x4*)&Vt[row * LT + cg * 4] = hv;
    }
    __syncthreads();

    // K out: [kt2][cs16][L][j] <- Kt[kt2*32 + (L&31)][cs16*16 + 8*(L>>5) + j]  (b128 reads)
    f16* kout = khs + (size_t)bh * 131072 + (size_t)(nt * 2) * 4096;
    #pragma unroll
    for (int it = 0; it < 4; ++it) {
        int slot = it * 256 + tid;
        int kt2 = slot >> 9, cs16 = (slot >> 6) & 7, L = slot & 63;
        int lq5 = L & 31, h = L >> 5;
        f16x8 kv = *(const f16x8*)&Kt[(kt2 * 32 + lq5) * LT + cs16 * 16 + 8 * h];
        *(f16x8*)(kout + (size_t)kt2 * 4096 + cs16 * 512 + L * 8) = kv;
    }
    // V out: [kt2][cb][kh][L][j] <- Vt[kt2*32 + kh*16 + 8*(L>>5) + j][cb*32 + (L&31)]
    f16* vout = vhs + (size_t)bh * 131072 + (size_t)(nt * 2) * 4096;
    #pragma unroll
    for (int it = 0; it < 4; ++it) {
        int slot = it * 256 + tid;
        int kt2 = slot >> 9, cb = (slot >> 7) & 3, kh = (slot >> 6) & 1, L = slot & 63;
        int lq5 = L & 31, h = L >> 5;
        int c = cb * 32 + lq5;
        f16x8 o;
        #pragma unroll
        for (int j = 0; j < 8; ++j)
            o[j] = Vt[(kt2 * 32 + kh * 16 + 8 * h + j) * LT + c];
        *(f16x8*)(vout + (size_t)kt2 * 4096 + (cb * 2 + kh) * 512 + L * 8) = o;
    }
}

static __device__ __forceinline__ unsigned pk2(f16 a, f16 b) {
    union { f16x2 h; unsigned u; } x; x.h = (f16x2){a, b}; return x.u;
}

// --------- attention: 32x32 swapped-QK^T, DIRECT global fragments, no LDS/barriers ---------
// 2x2 ablation completion: (global-path, 32x32). 16 B/pair through the vmem path (half of
// R0's 32), zero barriers, zero LDS. Two 32-key tiles per softmax block (64-key exact
// online math): two independent 8-deep QK^T MFMA chains fill the matrix pipe; barrier-free
// dataflow lets the compiler pipeline next-iteration loads under softmax VALU.
__global__ __launch_bounds__(256)
void ipa_attn(const float* __restrict__ qg, const f16* __restrict__ khs,
              const f16* __restrict__ vhs, const float* __restrict__ Lm,
              float* __restrict__ out)
{
    const int n = blockIdx.x;                   // 512 blocks = 64 bh x 8 qblk
    const int bh = ((n & 7) << 3) | ((n >> 3) & 7);   // XCD-local bh octet (matches pre)
    const int b  = bh >> 3;
    const int tid = threadIdx.x;
    const int w = tid >> 6, lane = tid & 63;
    const int lq5 = lane & 31, hh = lane >> 5;
    const int qblk = n >> 6;                    // 0..7
    const int q0 = qblk * 128 + w * 32;         // wave owns 32 q-rows
    const f16* kbh = khs + (size_t)bh * 131072;
    const f16* vbh = vhs + (size_t)bh * 131072;
    const float sc2 = 0.12751744154226873f;     // (1/sqrt(128)) * log2(e)

    // ---- Q: load fp32, transform (M = eta L^T eta), scale, B-frags ----
    // qf[cs16]: lane l holds Q[q0 + (l&31)][c = cs16*16 + 8*hh + j]
    f16x8 qf[8];
    {
        int qrow = q0 + lq5;
        const float* Lr = Lm + ((size_t)b * NSEQ + qrow) * 16;
        const float* qp = qg + ((size_t)bh * NSEQ + qrow) * CD;
        float Lv[16];
        #pragma unroll
        for (int i = 0; i < 4; ++i) *(float4*)&Lv[i*4] = *(const float4*)(Lr + i*4);
        #pragma unroll
        for (int cs = 0; cs < 8; ++cs) {
            int c0 = cs * 16 + 8 * hh;
            float4 x0 = *(const float4*)(qp + c0);
            float4 x1 = *(const float4*)(qp + c0 + 4);
            if (c0 >= 8) {
                float t0 = x0.x, t1 = -x0.y, t2 = -x0.z, t3 = -x0.w;
                float4 y;
                y.x =  (Lv[0]*t0 + Lv[4]*t1 + Lv[8] *t2 + Lv[12]*t3);
                y.y = -(Lv[1]*t0 + Lv[5]*t1 + Lv[9] *t2 + Lv[13]*t3);
                y.z = -(Lv[2]*t0 + Lv[6]*t1 + Lv[10]*t2 + Lv[14]*t3);
                y.w = -(Lv[3]*t0 + Lv[7]*t1 + Lv[11]*t2 + Lv[15]*t3);
                x0 = y;
                t0 = x1.x; t1 = -x1.y; t2 = -x1.z; t3 = -x1.w;
                y.x =  (Lv[0]*t0 + Lv[4]*t1 + Lv[8] *t2 + Lv[12]*t3);
                y.y = -(Lv[1]*t0 + Lv[5]*t1 + Lv[9] *t2 + Lv[13]*t3);
                y.z = -(Lv[2]*t0 + Lv[6]*t1 + Lv[10]*t2 + Lv[14]*t3);
                y.w = -(Lv[3]*t0 + Lv[7]*t1 + Lv[11]*t2 + Lv[15]*t3);
                x1 = y;
            }
            qf[cs] = (f16x8){(f16)(x0.x*sc2), (f16)(x0.y*sc2), (f16)(x0.z*sc2), (f16)(x0.w*sc2),
                             (f16)(x1.x*sc2), (f16)(x1.y*sc2), (f16)(x1.z*sc2), (f16)(x1.w*sc2)};
        }
    }

    // O accumulators: lane l reg r of cb = O[c=32cb+(r&3)+8*(r>>2)+4hh][q=l&31]
    f32x16 oacc[4];
    #pragma unroll
    for (int cb = 0; cb < 4; ++cb)
        #pragma unroll
        for (int r = 0; r < 16; ++r) oacc[cb][r] = 0.f;
    float mrun = -1e30f, lrun = 0.f;

    for (int t16 = 0; t16 < 16; ++t16) {            // 64 keys per iteration (tiles A,B)
        const int tA = t16 * 2, tB = tA + 1;

        // QK^T: two independent 8-deep chains (A,B) — fills the MFMA pipe
        f32x16 sA, sB;
        #pragma unroll
        for (int r = 0; r < 16; ++r) { sA[r] = 0.f; sB[r] = 0.f; }
        #pragma unroll
        for (int cs = 0; cs < 8; ++cs) {
            f16x8 kfA = *(const f16x8*)(kbh + ((size_t)tA * 8 + cs) * 512 + lane * 8);
            f16x8 kfB = *(const f16x8*)(kbh + ((size_t)tB * 8 + cs) * 512 + lane * 8);
            sA = __builtin_amdgcn_mfma_f32_32x32x16_f16(kfA, qf[cs], sA, 0, 0, 0);
            sB = __builtin_amdgcn_mfma_f32_32x32x16_f16(kfB, qf[cs], sB, 0, 0, 0);
        }

        // exact 64-key online softmax: single max/rescale over both tiles
        float mx = fmaxf(sA[0], sB[0]);
        #pragma unroll
        for (int r = 1; r < 16; ++r) mx = fmaxf(mx, fmaxf(sA[r], sB[r]));
        mx = fmaxf(mx, __shfl_xor(mx, 32, 64));
        float mnew = fmaxf(mrun, mx);
        // defer-rescale (bit-exact): when no lane sees a new max, alpha==1 exactly
        if (!__all(mx <= mrun)) {
            float alpha = exp2f(mrun - mnew);
            lrun *= alpha;
            #pragma unroll
            for (int cb = 0; cb < 4; ++cb) oacc[cb] *= alpha;
            mrun = mnew;
        }
        float prA[16], prB[16];
        f16 phA[16], phB[16];
        #pragma unroll
        for (int r = 0; r < 16; ++r) {
            prA[r] = exp2f(sA[r] - mnew); phA[r] = (f16)prA[r];
            prB[r] = exp2f(sB[r] - mnew); phB[r] = (f16)prB[r];
        }
        float rs = 0.f;
        #pragma unroll
        for (int r = 0; r < 16; ++r) rs += prA[r] + prB[r];
        lrun += rs;                                 // own-half keys; partner added at epilogue

        // PA fragments per tile: PA_kh[j] = P[key=16kh+8hh+j]
        // j=0..3 from half0, 4..7 from half1, regs (j&3)+8kh+4*hh -> 2 shfl_xor(32) per kh
        f16x8 pfA[2], pfB[2];
        #pragma unroll
        for (int kh = 0; kh < 2; ++kh) {
            unsigned aA0 = pk2(phA[8*kh+0], phA[8*kh+1]);
            unsigned aA1 = pk2(phA[8*kh+2], phA[8*kh+3]);
            unsigned aB0 = pk2(phA[8*kh+4], phA[8*kh+5]);
            unsigned aB1 = pk2(phA[8*kh+6], phA[8*kh+7]);
            unsigned s0 = hh ? aA0 : aB0;
            unsigned s1 = hh ? aA1 : aB1;
            unsigned r0 = __shfl_xor(s0, 32, 64);
            unsigned r1 = __shfl_xor(s1, 32, 64);
            union { unsigned u[4]; f16x8 h; } pw;
            pw.u[0] = hh ? r0 : aA0;
            pw.u[1] = hh ? r1 : aA1;
            pw.u[2] = hh ? aB0 : r0;
            pw.u[3] = hh ? aB1 : r1;
            pfA[kh] = pw.h;

            unsigned bA0 = pk2(phB[8*kh+0], phB[8*kh+1]);
            unsigned bA1 = pk2(phB[8*kh+2], phB[8*kh+3]);
            unsigned bB0 = pk2(phB[8*kh+4], phB[8*kh+5]);
            unsigned bB1 = pk2(phB[8*kh+6], phB[8*kh+7]);
            unsigned t0 = hh ? bA0 : bB0;
            unsigned t1 = hh ? bA1 : bB1;
            unsigned u0 = __shfl_xor(t0, 32, 64);
            unsigned u1 = __shfl_xor(t1, 32, 64);
            union { unsigned u[4]; f16x8 h; } qw;
            qw.u[0] = hh ? u0 : bA0;
            qw.u[1] = hh ? u1 : bA1;
            qw.u[2] = hh ? bB0 : u0;
            qw.u[3] = hh ? bB1 : u1;
            pfB[kh] = qw.h;
        }

        // PV: 16 MFMA, 4 independent oacc chains (A-kh0 -> A-kh1 -> B-kh0 -> B-kh1 per cb)
        #pragma unroll
        for (int cb = 0; cb < 4; ++cb) {
            #pragma unroll
            for (int kh = 0; kh < 2; ++kh) {
                f16x8 vfA = *(const f16x8*)(vbh + ((size_t)tA * 8 + cb * 2 + kh) * 512 + lane * 8);
                oacc[cb] = __builtin_amdgcn_mfma_f32_32x32x16_f16(vfA, pfA[kh], oacc[cb], 0, 0, 0);
            }
            #pragma unroll
            for (int kh = 0; kh < 2; ++kh) {
                f16x8 vfB = *(const f16x8*)(vbh + ((size_t)tB * 8 + cb * 2 + kh) * 512 + lane * 8);
                oacc[cb] = __builtin_amdgcn_mfma_f32_32x32x16_f16(vfB, pfB[kh], oacc[cb], 0, 0, 0);
            }
        }
    }

    // ---- epilogue: combine halves' l, normalize, final transform (M = L), store ----
    {
        float l = lrun + __shfl_xor(lrun, 32, 64);
        float invl = 1.0f / l;
        int qrow = q0 + lq5;
        const float* Lr = Lm + ((size_t)b * NSEQ + qrow) * 16;
        float Lv[16];
        #pragma unroll
        for (int i = 0; i < 4; ++i) *(float4*)&Lv[i*4] = *(const float4*)(Lr + i*4);
        float* ob = out + ((size_t)bh * NSEQ + qrow) * CD;
        #pragma unroll
        for (int cb = 0; cb < 4; ++cb) {
            #pragma unroll
            for (int rg = 0; rg < 4; ++rg) {
                int c0 = cb * 32 + rg * 8 + 4 * hh;
                float o0 = oacc[cb][rg*4+0] * invl, o1 = oacc[cb][rg*4+1] * invl;
                float o2 = oacc[cb][rg*4+2] * invl, o3 = oacc[cb][rg*4+3] * invl;
                float4 r;
                if (c0 >= 8) {
                    r.x = Lv[0] *o0 + Lv[1] *o1 + Lv[2] *o2 + Lv[3] *o3;
                    r.y = Lv[4] *o0 + Lv[5] *o1 + Lv[6] *o2 + Lv[7] *o3;
                    r.z = Lv[8] *o0 + Lv[9] *o1 + Lv[10]*o2 + Lv[11]*o3;
                    r.w = Lv[12]*o0 + Lv[13]*o1 + Lv[14]*o2 + Lv[15]*o3;
                } else {
                    r.x = o0; r.y = o1; r.z = o2; r.w = o3;
                }
                *(float4*)(ob + c0) = r;
            }
        }
    }
}

extern "C" void kernel_launch(void* const* d_in, const int* in_sizes, int n_in,
                              void* d_out, int out_size, void* d_ws, size_t ws_size,
                              hipStream_t stream) {
    const float* q = (const float*)d_in[0];
    const float* k = (const float*)d_in[1];
    const float* v = (const float*)d_in[2];
    const float* L = (const float*)d_in[3];
    float* o = (float*)d_out;
    f16* khs = (f16*)d_ws;                       // 16.78 MB
    f16* vhs = khs + (size_t)64 * 131072;        // 16.78 MB
    dim3 grid1(64, 16);
    ipa_pre<<<grid1, 256, 0, stream>>>(k, v, L, khs, vhs);
    ipa_attn<<<512, 256, 0, stream>>>(q, khs, vhs, L, o);
}